// Round 16
// baseline (86.074 us; speedup 1.0000x reference)
//
#include <hip/hip_runtime.h>
#include <stdint.h>

// Shapes fixed by setup_inputs(): x [8192,512] f32, patterns [1024,512] f32,
// edges [7] f32. Outputs: [8192] argmax idx (as f32) ++ [8192] score (cnt/512).
//
// R16: R9's proven match structure, but each block quantizes its OWN 32 rows
// of x into LDS (16KB, transposed [c16][h][row] -> 2-way-conflict-free) --
// xcode2 (4MB write + 4MB read) is gone and prep shrinks to patterns-only
// (128 blocks, ~1us). B-codes read from LDS in the hot loop; pattern loads
// and everything else identical to R9 (85.4us best, exact).
#define NROW 8192
#define NPAT 1024

typedef unsigned long long u64;
typedef unsigned int u32;
typedef unsigned char u8;
typedef __attribute__((ext_vector_type(4))) int i32x4;
typedef __attribute__((ext_vector_type(8))) int i32x8;
typedef __attribute__((ext_vector_type(16))) float f32x16;

__device__ __forceinline__ u32 bin7(float v, float e0, float e1, float e2,
                                    float e3, float e4, float e5, float e6) {
  return (u32)((v > e0) + (v > e1) + (v > e2) + (v > e3) + (v > e4) +
               (v > e5) + (v > e6));
}

// Quantize 16 consecutive dims -> 16 code bytes, PRE-SHIFTED (bin*4).
__device__ __forceinline__ int4 quant16n(const float4* s4, float e0, float e1,
                                         float e2, float e3, float e4,
                                         float e5, float e6) {
  int4 out;
  int* od = &out.x;
#pragma unroll
  for (int q = 0; q < 4; ++q) {
    float4 a = s4[q];
    od[q] = (int)((bin7(a.x, e0, e1, e2, e3, e4, e5, e6) << 2) |
                  ((bin7(a.y, e0, e1, e2, e3, e4, e5, e6) << 2) << 8) |
                  ((bin7(a.z, e0, e1, e2, e3, e4, e5, e6) << 2) << 16) |
                  ((bin7(a.w, e0, e1, e2, e3, e4, e5, e6) << 2) << 24));
  }
  return out;
}

// ---------------------------------------------------------------------------
// Prep: PATTERNS ONLY now. 128 blocks x 256 thr. qpc2[c16][h][pat][8B]:
// 8 dims per cell, so a lane's k-half for one 16-dim chunk is ONE dwordx2.
// ---------------------------------------------------------------------------
__global__ __launch_bounds__(256) void prep_kernel(
    const float* __restrict__ patterns, const float* __restrict__ edges,
    u8* __restrict__ qpc2) {
  const float e0 = edges[0], e1 = edges[1], e2 = edges[2], e3 = edges[3],
              e4 = edges[4], e5 = edges[5], e6 = edges[6];
  const int j = blockIdx.x * 256 + threadIdx.x;  // 0..32767
  const int pat = j >> 5;
  const int c16 = j & 31;
  const float4* s4 = reinterpret_cast<const float4*>(
      patterns + ((size_t)pat << 9) + (c16 << 4));
  int4 cod = quant16n(s4, e0, e1, e2, e3, e4, e5, e6);
  const u64 lo = (u64)(u32)cod.x | ((u64)(u32)cod.y << 32);  // dims 0..7
  const u64 hi = (u64)(u32)cod.z | ((u64)(u32)cod.w << 32);  // dims 8..15
  *reinterpret_cast<u64*>(
      qpc2 + ((((size_t)c16 * 2 + 0) * 1024 + pat) << 3)) = lo;
  *reinterpret_cast<u64*>(
      qpc2 + ((((size_t)c16 * 2 + 1) * 1024 + pat) << 3)) = hi;
}

// Expand 4 dims (pre-shifted codes bin*4 in the 4 bytes of w) into 4 dwords
// of fp4 one-hot nibbles (1.0 = 0x2 at nibble bin). IDENTICAL for A and B.
__device__ __forceinline__ i32x4 expand4(u32 w) {
  i32x4 f;
  f[0] = (int)(2u << (w & 0xFFu));
  f[1] = (int)(2u << ((w >> 8) & 0xFFu));
  f[2] = (int)(2u << ((w >> 16) & 0xFFu));
  f[3] = (int)(2u << (w >> 24));
  return f;
}

__device__ __forceinline__ i32x8 make8(i32x4 v) {
  i32x8 r;
  r[0] = v[0]; r[1] = v[1]; r[2] = v[2]; r[3] = v[3];
  r[4] = 0; r[5] = 0; r[6] = 0; r[7] = 0;  // fp4 uses operand regs 0-3
  return r;
}

#define MFMA_FP4(A, B, C)                                                \
  __builtin_amdgcn_mfma_scale_f32_32x32x64_f8f6f4(                       \
      (A), (B), (C), 4, 4, 0, 0x7F7F7F7F, 0, 0x7F7F7F7F)

// ---------------------------------------------------------------------------
// Match+argmax. Grid 256 x 512 thr (8 waves, 1 block/CU, 2 waves/SIMD).
// Stage 0: block quantizes its own 32 rows of x into LDS codes
//   lds_codes[c16][h][row] (16KB; writes/reads 2-way bank aliasing = free).
// Hot loop (R9 verbatim otherwise): B-code from LDS ds_read_b64; 4 pattern
// u64 loads (depth-1 prefetch); in-register fp4 expand; 8 MFMAs per chunk.
// Epilogue: packed keys -> LDS+shuffle argmax, wave 0 writes out[] directly.
// ---------------------------------------------------------------------------
__global__ __launch_bounds__(512, 2) void match_kernel(
    const float* __restrict__ x,    // [8192][512] f32
    const float* __restrict__ edges,
    const u8* __restrict__ qpc2,    // [32][2][1024][8]
    float* __restrict__ out) {
  __shared__ u64 lds_codes[32][2][32];  // [c16][h][row] 16 KB
  __shared__ u32 lds_best[8][64];       // 2 KB

  const int tid = threadIdx.x;
  const int lane = tid & 63;
  const int h = lane >> 5;
  const int wid = tid >> 6;  // 0..7
  const int rbase = blockIdx.x * 32;
  const int row = rbase + (lane & 31);
  const int m0 = wid * 128 + (lane & 31);

  // Stage 0: quantize own rows. Thread t handles cells i = t, t+512;
  // c16 = i>>5, r = i&31 (lanes sweep rows -> LDS stride 8B, 2-way, free).
  {
    const float e0 = edges[0], e1 = edges[1], e2 = edges[2], e3 = edges[3],
                e4 = edges[4], e5 = edges[5], e6 = edges[6];
#pragma unroll
    for (int rep = 0; rep < 2; ++rep) {
      const int i = tid + rep * 512;  // 0..1023
      const int c16 = i >> 5;
      const int r = i & 31;
      const float4* s4 = reinterpret_cast<const float4*>(
          x + ((size_t)(rbase + r) << 9) + (c16 << 4));
      int4 cod = quant16n(s4, e0, e1, e2, e3, e4, e5, e6);
      lds_codes[c16][0][r] = (u64)(u32)cod.x | ((u64)(u32)cod.y << 32);
      lds_codes[c16][1][r] = (u64)(u32)cod.z | ((u64)(u32)cod.w << 32);
    }
  }
  __syncthreads();

  const u8* pP = qpc2 + (((size_t)h * 1024 + m0) << 3);

  f32x16 acc0 = {0}, acc1 = {0}, acc2 = {0}, acc3 = {0};

  u64 cP0 = *reinterpret_cast<const u64*>(pP);
  u64 cP1 = *reinterpret_cast<const u64*>(pP + 256);
  u64 cP2 = *reinterpret_cast<const u64*>(pP + 512);
  u64 cP3 = *reinterpret_cast<const u64*>(pP + 768);

  for (int c = 0; c < 32; ++c) {
    const u64 cR = lds_codes[c][h][lane & 31];
    u64 nP0, nP1, nP2, nP3;
    if (c < 31) {
      const size_t po = (size_t)(c + 1) << 14;  // 2*1024*8 B per chunk
      nP0 = *reinterpret_cast<const u64*>(pP + po);
      nP1 = *reinterpret_cast<const u64*>(pP + po + 256);
      nP2 = *reinterpret_cast<const u64*>(pP + po + 512);
      nP3 = *reinterpret_cast<const u64*>(pP + po + 768);
    }
#pragma unroll
    for (int j = 0; j < 2; ++j) {
      const i32x8 b8 = make8(expand4((u32)(cR >> (32 * j))));
      const i32x8 a0 = make8(expand4((u32)(cP0 >> (32 * j))));
      const i32x8 a1 = make8(expand4((u32)(cP1 >> (32 * j))));
      const i32x8 a2 = make8(expand4((u32)(cP2 >> (32 * j))));
      const i32x8 a3 = make8(expand4((u32)(cP3 >> (32 * j))));
      acc0 = MFMA_FP4(a0, b8, acc0);
      acc1 = MFMA_FP4(a1, b8, acc1);
      acc2 = MFMA_FP4(a2, b8, acc2);
      acc3 = MFMA_FP4(a3, b8, acc3);
    }
    if (c < 31) {
      cP0 = nP0;
      cP1 = nP1;
      cP2 = nP2;
      cP3 = nP3;
    }
  }

  // Fold accs -> one packed key. C/D map (shape-determined, HW-verified):
  // col = lane&31 (this lane's row), pl = (r&3) + 8*(r>>2) + 4*h.
  const int hq = h << 2;
  const int wbase = wid * 128;
  u32 best = 0;
#pragma unroll
  for (int r = 0; r < 16; ++r) {
    const int pl = (r & 3) + 8 * (r >> 2) + hq;
    const u32 k0 = (((u32)acc0[r]) << 10) | (1023u - (u32)(wbase + pl));
    const u32 k1 = (((u32)acc1[r]) << 10) | (1023u - (u32)(wbase + 32 + pl));
    const u32 k2 = (((u32)acc2[r]) << 10) | (1023u - (u32)(wbase + 64 + pl));
    const u32 k3 = (((u32)acc3[r]) << 10) | (1023u - (u32)(wbase + 96 + pl));
    best = k0 > best ? k0 : best;
    best = k1 > best ? k1 : best;
    best = k2 > best ? k2 : best;
    best = k3 > best ? k3 : best;
  }
  lds_best[wid][lane] = best;
  __syncthreads();

  if (wid == 0) {
    u32 t = lds_best[0][lane];
#pragma unroll
    for (int w = 1; w < 8; ++w) {
      const u32 v = lds_best[w][lane];
      t = v > t ? v : t;
    }
    const u32 o = __shfl_down(t, 32);
    if (lane < 32) {
      const u32 f = o > t ? o : t;
      out[row] = (float)(1023u - (f & 1023u));
      out[NROW + row] = (float)(f >> 10) * (1.0f / 512.0f);
    }
  }
}

extern "C" void kernel_launch(void* const* d_in, const int* in_sizes, int n_in,
                              void* d_out, int out_size, void* d_ws,
                              size_t ws_size, hipStream_t stream) {
  const float* x = (const float*)d_in[0];         // [8192, 512]
  const float* patterns = (const float*)d_in[1];  // [1024, 512]
  const float* edges = (const float*)d_in[2];     // [7]
  float* out = (float*)d_out;                     // 16384 floats

  // Workspace: qpc2 512KB only.
  u8* qpc2 = (u8*)d_ws;  // [32][2][1024][8]

  prep_kernel<<<128, 256, 0, stream>>>(patterns, edges, qpc2);
  match_kernel<<<256, 512, 0, stream>>>(x, edges, qpc2, out);
}